// Round 1
// baseline (1850.140 us; speedup 1.0000x reference)
//
#include <hip/hip_runtime.h>
#include <cstdint>
#include <cstddef>

typedef unsigned int u32;

#define B_   2
#define L_   2048
#define D_   1024
#define NH_  16
#define KVH_ 8
#define DH_  64
#define TOPK_ 1024

// order-preserving float->uint key (descending float == descending uint)
__device__ __forceinline__ u32 fkey(float s) {
    u32 b = __float_as_uint(s);
    return b ^ ((u32)((int)b >> 31) | 0x80000000u);
}

// ---------------------------------------------------------------------------
// Generic tiled fp32 GEMM: C[M][N] = A[M][K] @ W[K][N]
// BM=64, BN=128, BK=16, 256 threads, thread tile 4x8.
// grid = (M/64, N/128)
// ---------------------------------------------------------------------------
__global__ __launch_bounds__(256) void gemm_tile(
    const float* __restrict__ A, const float* __restrict__ W,
    float* __restrict__ C, int K, int N) {
    __shared__ __align__(16) float As[16 * 64];    // [k][m]
    __shared__ __align__(16) float Bs[16 * 128];   // [k][n]
    int t  = threadIdx.x;
    int tx = t & 15, ty = t >> 4;
    int m0 = blockIdx.x * 64;
    int n0 = blockIdx.y * 128;

    float acc[4][8];
#pragma unroll
    for (int i = 0; i < 4; ++i)
#pragma unroll
        for (int j = 0; j < 8; ++j) acc[i][j] = 0.f;

    int aRow = t >> 2, aK4 = (t & 3) * 4;
    int bRow = t >> 4, bCol = (t & 15) * 8;

    for (int k0 = 0; k0 < K; k0 += 16) {
        float4 av = *(const float4*)(A + (size_t)(m0 + aRow) * K + k0 + aK4);
        As[(aK4 + 0) * 64 + aRow] = av.x;
        As[(aK4 + 1) * 64 + aRow] = av.y;
        As[(aK4 + 2) * 64 + aRow] = av.z;
        As[(aK4 + 3) * 64 + aRow] = av.w;
        float4 b0 = *(const float4*)(W + (size_t)(k0 + bRow) * N + n0 + bCol);
        float4 b1 = *(const float4*)(W + (size_t)(k0 + bRow) * N + n0 + bCol + 4);
        *(float4*)&Bs[bRow * 128 + bCol]     = b0;
        *(float4*)&Bs[bRow * 128 + bCol + 4] = b1;
        __syncthreads();
#pragma unroll
        for (int kk = 0; kk < 16; ++kk) {
            float4 af  = *(float4*)&As[kk * 64 + ty * 4];
            float4 bf0 = *(float4*)&Bs[kk * 128 + tx * 8];
            float4 bf1 = *(float4*)&Bs[kk * 128 + tx * 8 + 4];
            float a_[4] = {af.x, af.y, af.z, af.w};
            float b_[8] = {bf0.x, bf0.y, bf0.z, bf0.w, bf1.x, bf1.y, bf1.z, bf1.w};
#pragma unroll
            for (int i = 0; i < 4; ++i)
#pragma unroll
                for (int j = 0; j < 8; ++j)
                    acc[i][j] = fmaf(a_[i], b_[j], acc[i][j]);
        }
        __syncthreads();
    }
#pragma unroll
    for (int i = 0; i < 4; ++i) {
        float4 o0 = {acc[i][0], acc[i][1], acc[i][2], acc[i][3]};
        float4 o1 = {acc[i][4], acc[i][5], acc[i][6], acc[i][7]};
        size_t r = (size_t)(m0 + ty * 4 + i) * N + n0 + tx * 8;
        *(float4*)(C + r)     = o0;
        *(float4*)(C + r + 4) = o1;
    }
}

// ---------------------------------------------------------------------------
// RoPE on Q, in place. Layout [b][l][h][d]. One thread per (b,l,h,dl<32) pair.
// total threads = B*L*NH*32 = 2^21
// ---------------------------------------------------------------------------
__global__ __launch_bounds__(256) void rope_q(float* __restrict__ Q,
                                              const int* __restrict__ pos) {
    int tid = blockIdx.x * 256 + threadIdx.x;
    int dl = tid & 31;
    int h  = (tid >> 5) & 15;
    int l  = (tid >> 9) & 2047;
    int b  = tid >> 20;
    size_t base = ((size_t)(b * L_ + l) * NH_ + h) * DH_;
    float x1 = Q[base + dl];
    float x2 = Q[base + dl + 32];
    float p = (float)pos[b * L_ + l];
    float invf = (float)pow(10000.0, -(double)dl / 32.0);
    float a = p * invf;
    float s, c;
    sincosf(a, &s, &c);
    Q[base + dl]      = x1 * c - x2 * s;
    Q[base + dl + 32] = x2 * c + x1 * s;
}

// ---------------------------------------------------------------------------
// RoPE on K + transpose: Kraw[b][l][kvh][d] -> Kt[b][kvh][d][l]
// One thread per OUTPUT element. total = B*KVH*DH*L = 2^21
// ---------------------------------------------------------------------------
__global__ __launch_bounds__(256) void rope_kt(const float* __restrict__ Kraw,
                                               float* __restrict__ Kt,
                                               const int* __restrict__ pos) {
    int tid = blockIdx.x * 256 + threadIdx.x;
    int l   = tid & 2047;
    int d   = (tid >> 11) & 63;
    int kvh = (tid >> 17) & 7;
    int b   = tid >> 20;
    size_t src = ((size_t)(b * L_ + l) * KVH_ + kvh) * DH_;
    float x  = Kraw[src + d];
    int dp   = (d < 32) ? d + 32 : d - 32;
    float xp = Kraw[src + dp];
    float p = (float)pos[b * L_ + l];
    int i = d & 31;
    float invf = (float)pow(10000.0, -(double)i / 32.0);
    float a = p * invf;
    float s, c;
    sincosf(a, &s, &c);
    float out = (d < 32) ? (x * c - xp * s) : (x * c + xp * s);
    Kt[((size_t)((b * KVH_ + kvh) * DH_ + d)) * L_ + l] = out;
}

// ---------------------------------------------------------------------------
// Fused attention for 4 query rows per block.
// grid = B*NH*(L/4) = 16384, 256 threads.
// QR  [b][l][h][d]  (roped Q)
// Kt  [b][kvh][d][l]
// V   [b][l][kvh][d] (raw V)
// AO  [b][l][h][d]
// ---------------------------------------------------------------------------
__global__ __launch_bounds__(256) void attn(
    const float* __restrict__ QR, const float* __restrict__ Kt,
    const float* __restrict__ V, float* __restrict__ AO) {
    __shared__ __align__(16) float ql[4 * 64];
    __shared__ float pl[4 * 2048];
    __shared__ u32 hist[4 * 256];
    __shared__ u32 eqbuf[2048];
    __shared__ u32 sPref[4], sK[4], sNgt[4], sEqTot[4], eqCnt;
    __shared__ float wred[16];

    int t   = threadIdx.x;
    int bid = blockIdx.x;
    int l0  = (bid & 511) * 4;
    int h   = (bid >> 9) & 15;
    int b   = bid >> 13;
    int kvh = h >> 1;            // repeat_kv: q-head h uses kv-head h/GROUPS
    int lane = t & 63, w = t >> 6;

    // load 4 q rows
    {
        int q = t >> 6, d = t & 63;
        ql[q * 64 + d] = QR[((size_t)(b * L_ + l0 + q) * NH_ + h) * DH_ + d];
    }
    if (t < 4) { sK[t] = TOPK_; sPref[t] = 0u; sNgt[t] = 0u; }
    __syncthreads();

    // ---- QK^T: scores in registers, S[q][c] is score(row l0+q, col c*256+t)
    float S[4][8];
#pragma unroll
    for (int q = 0; q < 4; ++q)
#pragma unroll
        for (int c = 0; c < 8; ++c) S[q][c] = 0.f;

    const float* kbase = Kt + (size_t)(b * KVH_ + kvh) * DH_ * L_;
    for (int d = 0; d < 64; ++d) {
        float q0 = ql[0 * 64 + d], q1 = ql[1 * 64 + d];
        float q2 = ql[2 * 64 + d], q3 = ql[3 * 64 + d];
        const float* kr = kbase + (size_t)d * L_ + t;
#pragma unroll
        for (int c = 0; c < 8; ++c) {
            float kv = kr[c * 256];
            S[0][c] = fmaf(q0, kv, S[0][c]);
            S[1][c] = fmaf(q1, kv, S[1][c]);
            S[2][c] = fmaf(q2, kv, S[2][c]);
            S[3][c] = fmaf(q3, kv, S[3][c]);
        }
    }
#pragma unroll
    for (int q = 0; q < 4; ++q)
#pragma unroll
        for (int c = 0; c < 8; ++c) S[q][c] *= 0.125f;   // DH^-0.5

    // ---- exact top-1024 per row: 4-pass 8-bit radix select on fkey
    for (int pass = 0; pass < 4; ++pass) {
        int shift = 24 - 8 * pass;
        hist[t] = 0u; hist[256 + t] = 0u; hist[512 + t] = 0u; hist[768 + t] = 0u;
        __syncthreads();
        u32 pm = pass ? (0xFFFFFFFFu << (shift + 8)) : 0u;
#pragma unroll
        for (int q = 0; q < 4; ++q) {
            u32 pf = sPref[q];
#pragma unroll
            for (int c = 0; c < 8; ++c) {
                u32 u = fkey(S[q][c]);
                if ((u & pm) == pf)
                    atomicAdd(&hist[q * 256 + ((u >> shift) & 255)], 1u);
            }
        }
        __syncthreads();
        // wave w resolves row q=w: suffix scan of 256 bins (4 per lane)
        {
            u32* hq = &hist[w * 256];
            u32 h0 = hq[4 * lane], h1 = hq[4 * lane + 1];
            u32 h2 = hq[4 * lane + 2], h3 = hq[4 * lane + 3];
            u32 s4 = h0 + h1 + h2 + h3;
            u32 v = s4;
            for (int off = 1; off < 64; off <<= 1) {
                u32 tmp = __shfl_down(v, off);
                if (lane + off < 64) v += tmp;
            }
            u32 g = v - s4;          // count with digit > 4*lane+3
            u32 kq = sK[w];
            u32 hb_[4] = {h0, h1, h2, h3};
#pragma unroll
            for (int bb = 3; bb >= 0; --bb) {
                u32 hb = hb_[bb];
                if (hb && g < kq && kq <= g + hb) {
                    sPref[w] = sPref[w] | ((u32)(4 * lane + bb) << shift);
                    sK[w]    = kq - g;
                    sNgt[w]  = sNgt[w] + g;
                }
                g += hb;
            }
        }
        __syncthreads();
    }

    // ---- build selection masks with exact tie handling (lowest index wins)
    u32 selb[4] = {0u, 0u, 0u, 0u};
    if (t < 4) sEqTot[t] = 0u;
    __syncthreads();
#pragma unroll
    for (int q = 0; q < 4; ++q) {
        u32 uth = sPref[q];
        int e = 0;
#pragma unroll
        for (int c = 0; c < 8; ++c) {
            u32 u = fkey(S[q][c]);
            if (u > uth) selb[q] |= (1u << c);
            else if (u == uth) e++;
        }
        if (e) atomicAdd(&sEqTot[q], (u32)e);
    }
    __syncthreads();
    for (int q = 0; q < 4; ++q) {
        u32 uth = sPref[q];
        u32 quo = (u32)TOPK_ - sNgt[q];
        if (sEqTot[q] == quo) {      // common case: take every tied entry
#pragma unroll
            for (int c = 0; c < 8; ++c)
                if (fkey(S[q][c]) == uth) selb[q] |= (1u << c);
        } else {                     // rare: rank tied entries by index
            if (t == 0) eqCnt = 0u;
            __syncthreads();
#pragma unroll
            for (int c = 0; c < 8; ++c)
                if (fkey(S[q][c]) == uth) {
                    u32 idx = atomicAdd(&eqCnt, 1u);
                    if (idx < 2048u) eqbuf[idx] = (u32)(c * 256 + t);
                }
            __syncthreads();
            u32 m = eqCnt; if (m > 2048u) m = 2048u;
#pragma unroll
            for (int c = 0; c < 8; ++c)
                if (fkey(S[q][c]) == uth) {
                    u32 j = (u32)(c * 256 + t);
                    u32 r = 0;
                    for (u32 i = 0; i < m; ++i)
                        if (eqbuf[i] < j) r++;
                    if (r < quo) selb[q] |= (1u << c);
                }
            __syncthreads();
        }
    }

    // ---- softmax over selected entries; probs -> pl (0 elsewhere)
    float mx[4];
#pragma unroll
    for (int q = 0; q < 4; ++q) {
        float m_ = -3.4e38f;
#pragma unroll
        for (int c = 0; c < 8; ++c) m_ = fmaxf(m_, S[q][c]);
        for (int off = 1; off < 64; off <<= 1)
            m_ = fmaxf(m_, __shfl_xor(m_, off));
        if (lane == 0) wred[w * 4 + q] = m_;
    }
    __syncthreads();
#pragma unroll
    for (int q = 0; q < 4; ++q)
        mx[q] = fmaxf(fmaxf(wred[q], wred[4 + q]), fmaxf(wred[8 + q], wred[12 + q]));
    __syncthreads();
#pragma unroll
    for (int q = 0; q < 4; ++q) {
        float z = 0.f;
#pragma unroll
        for (int c = 0; c < 8; ++c) {
            float e = ((selb[q] >> c) & 1u) ? __expf(S[q][c] - mx[q]) : 0.f;
            S[q][c] = e;
            z += e;
        }
        for (int off = 1; off < 64; off <<= 1) z += __shfl_xor(z, off);
        if (lane == 0) wred[w * 4 + q] = z;
    }
    __syncthreads();
#pragma unroll
    for (int q = 0; q < 4; ++q) {
        float Zt = wred[q] + wred[4 + q] + wred[8 + q] + wred[12 + q];
        float inv = 1.0f / Zt;
#pragma unroll
        for (int c = 0; c < 8; ++c)
            pl[q * 2048 + c * 256 + t] = S[q][c] * inv;
    }
    __syncthreads();

    // ---- PV: thread = (q = t>>6, js = (t>>4)&3, d4 = (t&15)*4)
    {
        int q  = t >> 6;
        int js = (t >> 4) & 3;
        int d4 = (t & 15) * 4;
        const float* vbase = V + (size_t)(b * L_) * KVH_ * DH_ + kvh * DH_ + d4;
        float a0 = 0.f, a1 = 0.f, a2 = 0.f, a3 = 0.f;
        for (int jj = 0; jj < 512; ++jj) {
            int j = jj * 4 + js;
            float4 vv = *(const float4*)(vbase + (size_t)j * (KVH_ * DH_));
            float p = pl[q * 2048 + j];
            a0 = fmaf(p, vv.x, a0);
            a1 = fmaf(p, vv.y, a1);
            a2 = fmaf(p, vv.z, a2);
            a3 = fmaf(p, vv.w, a3);
        }
        a0 += __shfl_xor(a0, 16); a1 += __shfl_xor(a1, 16);
        a2 += __shfl_xor(a2, 16); a3 += __shfl_xor(a3, 16);
        a0 += __shfl_xor(a0, 32); a1 += __shfl_xor(a1, 32);
        a2 += __shfl_xor(a2, 32); a3 += __shfl_xor(a3, 32);
        if (js == 0) {
            float4 o = {a0, a1, a2, a3};
            *(float4*)(AO + ((size_t)(b * L_ + l0 + q) * NH_ + h) * DH_ + d4) = o;
        }
    }
}

// ---------------------------------------------------------------------------
extern "C" void kernel_launch(void* const* d_in, const int* in_sizes, int n_in,
                              void* d_out, int out_size, void* d_ws, size_t ws_size,
                              hipStream_t stream) {
    const float* hs = (const float*)d_in[0];   // [B,L,D]
    const float* wq = (const float*)d_in[1];   // [D, NH*DH]
    const float* wk = (const float*)d_in[2];   // [D, KVH*DH]
    const float* wv = (const float*)d_in[3];   // [D, KVH*DH]
    const float* wo = (const float*)d_in[4];   // [NH*DH, D]
    const int*  pos = (const int*)d_in[5];     // [B,L] int32

    float* ws   = (float*)d_ws;
    float* Qraw = ws;                    // 4096*1024  (16 MB)
    float* Kraw = Qraw + 4194304;        // 4096*512   ( 8 MB)
    float* Vraw = Kraw + 2097152;        // 4096*512   ( 8 MB)
    float* Kt   = Vraw + 2097152;        // 2*8*64*2048( 8 MB)
    float* AO   = Kt   + 2097152;        // 4096*1024  (16 MB)
    float* out  = (float*)d_out;

    dim3 blk(256);
    // QKV projections
    gemm_tile<<<dim3(64, 8), blk, 0, stream>>>(hs, wq, Qraw, 1024, 1024);
    gemm_tile<<<dim3(64, 4), blk, 0, stream>>>(hs, wk, Kraw, 1024, 512);
    gemm_tile<<<dim3(64, 4), blk, 0, stream>>>(hs, wv, Vraw, 1024, 512);
    // RoPE (+ K transpose)
    rope_q <<<dim3(8192), blk, 0, stream>>>(Qraw, pos);
    rope_kt<<<dim3(8192), blk, 0, stream>>>(Kraw, Kt, pos);
    // fused sparse attention
    attn<<<dim3(16384), blk, 0, stream>>>(Qraw, Kt, Vraw, AO);
    // output projection
    gemm_tile<<<dim3(64, 8), blk, 0, stream>>>(AO, wo, out, 1024, 1024);
}

// Round 2
// 1327.331 us; speedup vs baseline: 1.3939x; 1.3939x over previous
//
#include <hip/hip_runtime.h>
#include <cstdint>
#include <cstddef>

typedef unsigned int u32;
typedef __attribute__((ext_vector_type(8))) short s8v;   // 8 bf16 (4 VGPRs)
typedef __attribute__((ext_vector_type(4))) float f4v;   // MFMA C/D

#define B_   2
#define L_   2048
#define D_   1024
#define NH_  16
#define KVH_ 8
#define DH_  64
#define TOPK_ 1024

#define MFMA16(a, b, c) __builtin_amdgcn_mfma_f32_16x16x32_bf16(a, b, c, 0, 0, 0)

// order-preserving float->uint key (descending float == descending uint)
__device__ __forceinline__ u32 fkey(float s) {
    u32 b = __float_as_uint(s);
    return b ^ ((u32)((int)b >> 31) | 0x80000000u);
}
// fp32 -> bf16 round-to-nearest-even, as raw ushort
__device__ __forceinline__ unsigned short bf16rne(float x) {
    u32 u = __float_as_uint(x);
    u32 r = (u + 0x7FFFu + ((u >> 16) & 1u)) >> 16;
    return (unsigned short)r;
}

// ---------------------------------------------------------------------------
// Generic tiled fp32 GEMM: C[M][N] = A[M][K] @ W[K][N]  (unchanged from R1)
// ---------------------------------------------------------------------------
__global__ __launch_bounds__(256) void gemm_tile(
    const float* __restrict__ A, const float* __restrict__ W,
    float* __restrict__ C, int K, int N) {
    __shared__ __align__(16) float As[16 * 64];
    __shared__ __align__(16) float Bs[16 * 128];
    int t  = threadIdx.x;
    int tx = t & 15, ty = t >> 4;
    int m0 = blockIdx.x * 64;
    int n0 = blockIdx.y * 128;

    float acc[4][8];
#pragma unroll
    for (int i = 0; i < 4; ++i)
#pragma unroll
        for (int j = 0; j < 8; ++j) acc[i][j] = 0.f;

    int aRow = t >> 2, aK4 = (t & 3) * 4;
    int bRow = t >> 4, bCol = (t & 15) * 8;

    for (int k0 = 0; k0 < K; k0 += 16) {
        float4 av = *(const float4*)(A + (size_t)(m0 + aRow) * K + k0 + aK4);
        As[(aK4 + 0) * 64 + aRow] = av.x;
        As[(aK4 + 1) * 64 + aRow] = av.y;
        As[(aK4 + 2) * 64 + aRow] = av.z;
        As[(aK4 + 3) * 64 + aRow] = av.w;
        float4 b0 = *(const float4*)(W + (size_t)(k0 + bRow) * N + n0 + bCol);
        float4 b1 = *(const float4*)(W + (size_t)(k0 + bRow) * N + n0 + bCol + 4);
        *(float4*)&Bs[bRow * 128 + bCol]     = b0;
        *(float4*)&Bs[bRow * 128 + bCol + 4] = b1;
        __syncthreads();
#pragma unroll
        for (int kk = 0; kk < 16; ++kk) {
            float4 af  = *(float4*)&As[kk * 64 + ty * 4];
            float4 bf0 = *(float4*)&Bs[kk * 128 + tx * 8];
            float4 bf1 = *(float4*)&Bs[kk * 128 + tx * 8 + 4];
            float a_[4] = {af.x, af.y, af.z, af.w};
            float b_[8] = {bf0.x, bf0.y, bf0.z, bf0.w, bf1.x, bf1.y, bf1.z, bf1.w};
#pragma unroll
            for (int i = 0; i < 4; ++i)
#pragma unroll
                for (int j = 0; j < 8; ++j)
                    acc[i][j] = fmaf(a_[i], b_[j], acc[i][j]);
        }
        __syncthreads();
    }
#pragma unroll
    for (int i = 0; i < 4; ++i) {
        float4 o0 = {acc[i][0], acc[i][1], acc[i][2], acc[i][3]};
        float4 o1 = {acc[i][4], acc[i][5], acc[i][6], acc[i][7]};
        size_t r = (size_t)(m0 + ty * 4 + i) * N + n0 + tx * 8;
        *(float4*)(C + r)     = o0;
        *(float4*)(C + r + 4) = o1;
    }
}

// ---------------------------------------------------------------------------
// RoPE on Q, in place. Layout [b][l][h][d].
// ---------------------------------------------------------------------------
__global__ __launch_bounds__(256) void rope_q(float* __restrict__ Q,
                                              const int* __restrict__ pos) {
    int tid = blockIdx.x * 256 + threadIdx.x;
    int dl = tid & 31;
    int h  = (tid >> 5) & 15;
    int l  = (tid >> 9) & 2047;
    int b  = tid >> 20;
    size_t base = ((size_t)(b * L_ + l) * NH_ + h) * DH_;
    float x1 = Q[base + dl];
    float x2 = Q[base + dl + 32];
    float p = (float)pos[b * L_ + l];
    float invf = (float)pow(10000.0, -(double)dl / 32.0);
    float a = p * invf;
    float s, c;
    sincosf(a, &s, &c);
    Q[base + dl]      = x1 * c - x2 * s;
    Q[base + dl + 32] = x2 * c + x1 * s;
}

// ---------------------------------------------------------------------------
// RoPE on K + hi/lo bf16 split, layout [b][kvh][l][d] (MFMA B-frag friendly)
// One thread per output element. total = B*KVH*L*DH = 2^21
// ---------------------------------------------------------------------------
__global__ __launch_bounds__(256) void prep_k(const float* __restrict__ Kraw,
                                              unsigned short* __restrict__ KHp,
                                              unsigned short* __restrict__ KLp,
                                              const int* __restrict__ pos) {
    int tid = blockIdx.x * 256 + threadIdx.x;
    int d   = tid & 63;
    int l   = (tid >> 6) & 2047;
    int kvh = (tid >> 17) & 7;
    int b   = tid >> 20;
    size_t src = ((size_t)(b * L_ + l) * KVH_ + kvh) * DH_;
    float x  = Kraw[src + d];
    int dp   = (d < 32) ? d + 32 : d - 32;
    float xp = Kraw[src + dp];
    float p = (float)pos[b * L_ + l];
    int i = d & 31;
    float invf = (float)pow(10000.0, -(double)i / 32.0);
    float a = p * invf;
    float s, c;
    sincosf(a, &s, &c);
    float out = (d < 32) ? (x * c - xp * s) : (x * c + xp * s);
    unsigned short hi = bf16rne(out);
    float hf = __uint_as_float((u32)hi << 16);
    unsigned short lo = bf16rne(out - hf);
    size_t dst = ((size_t)(b * KVH_ + kvh) * L_ + l) * DH_ + d;
    KHp[dst] = hi;
    KLp[dst] = lo;
}

// ---------------------------------------------------------------------------
// V transpose to bf16: Vraw[b][l][kvh][d] -> VT[b][kvh][d][l]
// 64x64 LDS tile per block; grid = (L/64) * KVH * B = 512
// ---------------------------------------------------------------------------
__global__ __launch_bounds__(256) void prep_v(const float* __restrict__ Vraw,
                                              unsigned short* __restrict__ VTp) {
    __shared__ float tile[64 * 65];
    int bid = blockIdx.x;
    int lb  = bid & 31;
    int kvh = (bid >> 5) & 7;
    int b   = bid >> 8;
    int l0  = lb * 64;
    int t   = threadIdx.x;
#pragma unroll
    for (int i = 0; i < 16; ++i) {
        int idx = t + i * 256;
        int ll = idx >> 6, d = idx & 63;
        tile[ll * 65 + d] = Vraw[((size_t)(b * L_ + l0 + ll) * KVH_ + kvh) * DH_ + d];
    }
    __syncthreads();
#pragma unroll
    for (int i = 0; i < 16; ++i) {
        int idx = t + i * 256;
        int d = idx >> 6, ll = idx & 63;
        VTp[((size_t)(b * KVH_ + kvh) * DH_ + d) * L_ + l0 + ll] = bf16rne(tile[ll * 65 + d]);
    }
}

// ---------------------------------------------------------------------------
// Fused sparse attention, 16 q-rows per block, MFMA QK (hi/lo) + MFMA PV.
// grid = B*NH*(L/16) = 4096, 256 threads (4 waves; wave w owns j in [512w,512w+512)).
// Score layout (MFMA C): S[tj][r] = score(q = quad*4+r, j = 512w + 16tj + col)
// ---------------------------------------------------------------------------
__global__ __launch_bounds__(256, 2) void attn(
    const float* __restrict__ QR,
    const unsigned short* __restrict__ KH,
    const unsigned short* __restrict__ KL,
    const unsigned short* __restrict__ VT,
    float* __restrict__ AO) {

    __shared__ __align__(16) union {
        struct { float qtile[16 * 68]; u32 eqbuf[2048]; } p0;  // phase0 + tie ranking
        u32 hist[16 * 256];                                    // radix
        float outred[4 * 1024];                                // epilogue
    } sm;
    __shared__ __align__(16) unsigned short Pbuf[4][16 * 136]; // per-wave P chunk (A-layout src)
    __shared__ u32 sPref[16], sK[16], sNgt[16], sEqTot[16];
    __shared__ float wredM[16][4], wredZ[16][4], sInvZ[16];
    __shared__ u32 sCM, sRM, eqCnt;

    const int t = threadIdx.x;
    const int lane = t & 63, w = t >> 6;
    const int quad = lane >> 4, col = lane & 15;
    const int bid = blockIdx.x;
    const int l0 = (bid & 127) * 16;
    const int h  = (bid >> 7) & 15;
    const int b  = bid >> 11;
    const int kvh = h >> 1;

    // ---- load Q tile (roped, fp32) into LDS
    {
        int q = t >> 4, d4 = (t & 15) * 4;
        *(float4*)&sm.p0.qtile[q * 68 + d4] =
            *(const float4*)(QR + ((size_t)((b * L_ + l0 + q) * NH_ + h)) * DH_ + d4);
    }
    if (t < 16) { sPref[t] = 0u; sNgt[t] = 0u; sK[t] = TOPK_; sEqTot[t] = 0u; }
    __syncthreads();

    // ---- build A-frags (hi/lo): A[m=col][k = ks*32 + quad*8 + i]
    union FR { s8v v; unsigned short u[8]; };
    FR ah[2], al[2];
#pragma unroll
    for (int ks = 0; ks < 2; ++ks)
#pragma unroll
        for (int i = 0; i < 8; ++i) {
            float x = sm.p0.qtile[col * 68 + ks * 32 + quad * 8 + i];
            unsigned short hi = bf16rne(x);
            float hf = __uint_as_float((u32)hi << 16);
            ah[ks].u[i] = hi;
            al[ks].u[i] = bf16rne(x - hf);
        }
    __syncthreads();   // qtile dead; union reusable

    // ---- QK^T via MFMA, 4-term hi/lo (fp32-class accuracy for exact top-k)
    const size_t slabK = (size_t)(b * KVH_ + kvh) * L_ * DH_;
    const unsigned short* khp = KH + slabK;
    const unsigned short* klp = KL + slabK;
    f4v S[32];
#pragma unroll
    for (int tj = 0; tj < 32; ++tj) {
        int j0 = w * 512 + tj * 16;
        const unsigned short* kh8 = khp + (size_t)(j0 + col) * 64 + quad * 8;
        const unsigned short* kl8 = klp + (size_t)(j0 + col) * 64 + quad * 8;
        s8v bh0 = *(const s8v*)(kh8);
        s8v bh1 = *(const s8v*)(kh8 + 32);
        s8v bl0 = *(const s8v*)(kl8);
        s8v bl1 = *(const s8v*)(kl8 + 32);
        f4v c = {0.f, 0.f, 0.f, 0.f};
        c = MFMA16(ah[0].v, bh0, c);
        c = MFMA16(ah[1].v, bh1, c);
        c = MFMA16(al[0].v, bh0, c);
        c = MFMA16(al[1].v, bh1, c);
        c = MFMA16(ah[0].v, bl0, c);
        c = MFMA16(ah[1].v, bl1, c);
        c = MFMA16(al[0].v, bl0, c);
        c = MFMA16(al[1].v, bl1, c);
        S[tj] = c * 0.125f;   // DH^-0.5
    }

    // ---- exact top-1024 per row: 4-pass 8-bit radix select on fkey
    for (int pass = 0; pass < 4; ++pass) {
        int shift = 24 - 8 * pass;
#pragma unroll
        for (int i = 0; i < 16; ++i) sm.hist[t * 16 + i] = 0u;
        __syncthreads();
        u32 pm  = pass ? (0xFFFFFFFFu << (shift + 8)) : 0u;
        u32 pf0 = sPref[quad * 4 + 0], pf1 = sPref[quad * 4 + 1];
        u32 pf2 = sPref[quad * 4 + 2], pf3 = sPref[quad * 4 + 3];
#pragma unroll
        for (int tj = 0; tj < 32; ++tj) {
            u32 u;
            u = fkey(S[tj][0]); if ((u & pm) == pf0) atomicAdd(&sm.hist[(quad * 4 + 0) * 256 + ((u >> shift) & 255)], 1u);
            u = fkey(S[tj][1]); if ((u & pm) == pf1) atomicAdd(&sm.hist[(quad * 4 + 1) * 256 + ((u >> shift) & 255)], 1u);
            u = fkey(S[tj][2]); if ((u & pm) == pf2) atomicAdd(&sm.hist[(quad * 4 + 2) * 256 + ((u >> shift) & 255)], 1u);
            u = fkey(S[tj][3]); if ((u & pm) == pf3) atomicAdd(&sm.hist[(quad * 4 + 3) * 256 + ((u >> shift) & 255)], 1u);
        }
        __syncthreads();
        // wave w resolves rows 4w..4w+3
#pragma unroll
        for (int rr = 0; rr < 4; ++rr) {
            int q = w * 4 + rr;
            u32* hq = &sm.hist[q * 256];
            u32 h0 = hq[4 * lane], h1 = hq[4 * lane + 1];
            u32 h2 = hq[4 * lane + 2], h3 = hq[4 * lane + 3];
            u32 s4 = h0 + h1 + h2 + h3;
            u32 v = s4;
            for (int off = 1; off < 64; off <<= 1) {
                u32 tmp = __shfl_down(v, off);
                if (lane + off < 64) v += tmp;
            }
            u32 g = v - s4;
            u32 kq = sK[q];
            u32 hb_[4] = {h0, h1, h2, h3};
#pragma unroll
            for (int bb = 3; bb >= 0; --bb) {
                u32 hb = hb_[bb];
                if (hb && g < kq && kq <= g + hb) {
                    sPref[q] |= ((u32)(4 * lane + bb)) << shift;
                    sK[q]   = kq - g;
                    sNgt[q] += g;
                }
                g += hb;
            }
        }
        __syncthreads();
    }

    // ---- selection masks (bit tj per reg r), exact tie handling
    u32 uth0 = sPref[quad * 4 + 0], uth1 = sPref[quad * 4 + 1];
    u32 uth2 = sPref[quad * 4 + 2], uth3 = sPref[quad * 4 + 3];
    u32 selb[4] = {0u, 0u, 0u, 0u};
    {
        u32 e0 = 0, e1 = 0, e2 = 0, e3 = 0;
#pragma unroll
        for (int tj = 0; tj < 32; ++tj) {
            u32 u;
            u = fkey(S[tj][0]); if (u > uth0) selb[0] |= 1u << tj; else if (u == uth0) e0++;
            u = fkey(S[tj][1]); if (u > uth1) selb[1] |= 1u << tj; else if (u == uth1) e1++;
            u = fkey(S[tj][2]); if (u > uth2) selb[2] |= 1u << tj; else if (u == uth2) e2++;
            u = fkey(S[tj][3]); if (u > uth3) selb[3] |= 1u << tj; else if (u == uth3) e3++;
        }
        if (e0) atomicAdd(&sEqTot[quad * 4 + 0], e0);
        if (e1) atomicAdd(&sEqTot[quad * 4 + 1], e1);
        if (e2) atomicAdd(&sEqTot[quad * 4 + 2], e2);
        if (e3) atomicAdd(&sEqTot[quad * 4 + 3], e3);
    }
    __syncthreads();
    if (t == 0) {
        u32 cm = 0, rm = 0;
        for (int q = 0; q < 16; ++q) {
            u32 quo = (u32)TOPK_ - sNgt[q];
            if (sEqTot[q] == quo) cm |= 1u << q; else rm |= 1u << q;
        }
        sCM = cm; sRM = rm;
    }
    __syncthreads();
    {
        u32 cm = sCM;
        bool c0 = (cm >> (quad * 4 + 0)) & 1u, c1 = (cm >> (quad * 4 + 1)) & 1u;
        bool c2 = (cm >> (quad * 4 + 2)) & 1u, c3 = (cm >> (quad * 4 + 3)) & 1u;
#pragma unroll
        for (int tj = 0; tj < 32; ++tj) {
            if (c0 && fkey(S[tj][0]) == uth0) selb[0] |= 1u << tj;
            if (c1 && fkey(S[tj][1]) == uth1) selb[1] |= 1u << tj;
            if (c2 && fkey(S[tj][2]) == uth2) selb[2] |= 1u << tj;
            if (c3 && fkey(S[tj][3]) == uth3) selb[3] |= 1u << tj;
        }
    }
    {   // rare rows: rank ties by lowest index
        u32 rm = sRM;
        for (int q = 0; q < 16; ++q) {
            if (!((rm >> q) & 1u)) continue;
            if (t == 0) eqCnt = 0u;
            __syncthreads();
            u32 uq = sPref[q];
            int qq = q >> 2, qr = q & 3;
            if (quad == qq) {
#pragma unroll
                for (int r = 0; r < 4; ++r) if (r == qr) {
#pragma unroll
                    for (int tj = 0; tj < 32; ++tj)
                        if (fkey(S[tj][r]) == uq) {
                            u32 idx = atomicAdd(&eqCnt, 1u);
                            if (idx < 2048u) sm.p0.eqbuf[idx] = (u32)(w * 512 + tj * 16 + col);
                        }
                }
            }
            __syncthreads();
            u32 m = eqCnt; if (m > 2048u) m = 2048u;
            u32 quo = (u32)TOPK_ - sNgt[q];
            if (quad == qq) {
#pragma unroll
                for (int r = 0; r < 4; ++r) if (r == qr) {
#pragma unroll
                    for (int tj = 0; tj < 32; ++tj)
                        if (fkey(S[tj][r]) == uq) {
                            u32 j = (u32)(w * 512 + tj * 16 + col);
                            u32 rk = 0;
                            for (u32 i = 0; i < m; ++i)
                                if (sm.p0.eqbuf[i] < j) rk++;
                            if (rk < quo) selb[r] |= 1u << tj;
                        }
                }
            }
            __syncthreads();
        }
    }

    // ---- softmax (row max over all scores; top element is always selected)
    float m0 = -3.4e38f, m1 = -3.4e38f, m2 = -3.4e38f, m3 = -3.4e38f;
#pragma unroll
    for (int tj = 0; tj < 32; ++tj) {
        m0 = fmaxf(m0, S[tj][0]); m1 = fmaxf(m1, S[tj][1]);
        m2 = fmaxf(m2, S[tj][2]); m3 = fmaxf(m3, S[tj][3]);
    }
    for (int off = 1; off < 16; off <<= 1) {
        m0 = fmaxf(m0, __shfl_xor(m0, off)); m1 = fmaxf(m1, __shfl_xor(m1, off));
        m2 = fmaxf(m2, __shfl_xor(m2, off)); m3 = fmaxf(m3, __shfl_xor(m3, off));
    }
    if (col == 0) {
        wredM[quad * 4 + 0][w] = m0; wredM[quad * 4 + 1][w] = m1;
        wredM[quad * 4 + 2][w] = m2; wredM[quad * 4 + 3][w] = m3;
    }
    __syncthreads();
    m0 = fmaxf(fmaxf(wredM[quad * 4 + 0][0], wredM[quad * 4 + 0][1]), fmaxf(wredM[quad * 4 + 0][2], wredM[quad * 4 + 0][3]));
    m1 = fmaxf(fmaxf(wredM[quad * 4 + 1][0], wredM[quad * 4 + 1][1]), fmaxf(wredM[quad * 4 + 1][2], wredM[quad * 4 + 1][3]));
    m2 = fmaxf(fmaxf(wredM[quad * 4 + 2][0], wredM[quad * 4 + 2][1]), fmaxf(wredM[quad * 4 + 2][2], wredM[quad * 4 + 2][3]));
    m3 = fmaxf(fmaxf(wredM[quad * 4 + 3][0], wredM[quad * 4 + 3][1]), fmaxf(wredM[quad * 4 + 3][2], wredM[quad * 4 + 3][3]));
    float z0 = 0.f, z1 = 0.f, z2 = 0.f, z3 = 0.f;
#pragma unroll
    for (int tj = 0; tj < 32; ++tj) {
        float e;
        e = ((selb[0] >> tj) & 1u) ? __expf(S[tj][0] - m0) : 0.f; S[tj][0] = e; z0 += e;
        e = ((selb[1] >> tj) & 1u) ? __expf(S[tj][1] - m1) : 0.f; S[tj][1] = e; z1 += e;
        e = ((selb[2] >> tj) & 1u) ? __expf(S[tj][2] - m2) : 0.f; S[tj][2] = e; z2 += e;
        e = ((selb[3] >> tj) & 1u) ? __expf(S[tj][3] - m3) : 0.f; S[tj][3] = e; z3 += e;
    }
    for (int off = 1; off < 16; off <<= 1) {
        z0 += __shfl_xor(z0, off); z1 += __shfl_xor(z1, off);
        z2 += __shfl_xor(z2, off); z3 += __shfl_xor(z3, off);
    }
    if (col == 0) {
        wredZ[quad * 4 + 0][w] = z0; wredZ[quad * 4 + 1][w] = z1;
        wredZ[quad * 4 + 2][w] = z2; wredZ[quad * 4 + 3][w] = z3;
    }
    __syncthreads();
    if (w == 0 && col == 0) {
#pragma unroll
        for (int r = 0; r < 4; ++r) {
            int q = quad * 4 + r;
            float Z = wredZ[q][0] + wredZ[q][1] + wredZ[q][2] + wredZ[q][3];
            sInvZ[q] = 1.f / Z;
        }
    }

    // ---- PV via MFMA: out[q][d] = sum_j P[q][j] V[j][d]; wave w does its own j-range.
    const unsigned short* vt = VT + (size_t)(b * KVH_ + kvh) * DH_ * L_;
    f4v acc0 = {0.f, 0.f, 0.f, 0.f}, acc1 = acc0, acc2 = acc0, acc3 = acc0;
    for (int cc = 0; cc < 4; ++cc) {
        // write P chunk (C-layout -> row-major [q][jl]) — wave-private region
#pragma unroll
        for (int tjl = 0; tjl < 8; ++tjl) {
            int tj = cc * 8 + tjl;
            Pbuf[w][(quad * 4 + 0) * 136 + tjl * 16 + col] = bf16rne(S[tj][0]);
            Pbuf[w][(quad * 4 + 1) * 136 + tjl * 16 + col] = bf16rne(S[tj][1]);
            Pbuf[w][(quad * 4 + 2) * 136 + tjl * 16 + col] = bf16rne(S[tj][2]);
            Pbuf[w][(quad * 4 + 3) * 136 + tjl * 16 + col] = bf16rne(S[tj][3]);
        }
        // same-wave DS ordering guarantees write->read consistency
#pragma unroll
        for (int ks = 0; ks < 4; ++ks) {
            s8v ap = *(const s8v*)&Pbuf[w][col * 136 + ks * 32 + quad * 8];
            int jb = w * 512 + cc * 128 + ks * 32 + quad * 8;
            s8v v0 = *(const s8v*)(vt + (size_t)( 0 + col) * L_ + jb);
            s8v v1 = *(const s8v*)(vt + (size_t)(16 + col) * L_ + jb);
            s8v v2 = *(const s8v*)(vt + (size_t)(32 + col) * L_ + jb);
            s8v v3 = *(const s8v*)(vt + (size_t)(48 + col) * L_ + jb);
            acc0 = MFMA16(ap, v0, acc0);
            acc1 = MFMA16(ap, v1, acc1);
            acc2 = MFMA16(ap, v2, acc2);
            acc3 = MFMA16(ap, v3, acc3);
        }
    }

    // ---- cross-wave reduction + invZ scale + store
#pragma unroll
    for (int r = 0; r < 4; ++r) {
        sm.outred[w * 1024 + (quad * 4 + r) * 64 +  0 + col] = acc0[r];
        sm.outred[w * 1024 + (quad * 4 + r) * 64 + 16 + col] = acc1[r];
        sm.outred[w * 1024 + (quad * 4 + r) * 64 + 32 + col] = acc2[r];
        sm.outred[w * 1024 + (quad * 4 + r) * 64 + 48 + col] = acc3[r];
    }
    __syncthreads();
    {
        int q = t >> 4, d4 = (t & 15) * 4;
        float4 o0 = *(float4*)&sm.outred[0 * 1024 + q * 64 + d4];
        float4 o1 = *(float4*)&sm.outred[1 * 1024 + q * 64 + d4];
        float4 o2 = *(float4*)&sm.outred[2 * 1024 + q * 64 + d4];
        float4 o3 = *(float4*)&sm.outred[3 * 1024 + q * 64 + d4];
        float iz = sInvZ[q];
        float4 o;
        o.x = (o0.x + o1.x + o2.x + o3.x) * iz;
        o.y = (o0.y + o1.y + o2.y + o3.y) * iz;
        o.z = (o0.z + o1.z + o2.z + o3.z) * iz;
        o.w = (o0.w + o1.w + o2.w + o3.w) * iz;
        *(float4*)(AO + ((size_t)((b * L_ + l0 + q) * NH_ + h)) * DH_ + d4) = o;
    }
}

// ---------------------------------------------------------------------------
extern "C" void kernel_launch(void* const* d_in, const int* in_sizes, int n_in,
                              void* d_out, int out_size, void* d_ws, size_t ws_size,
                              hipStream_t stream) {
    const float* hs = (const float*)d_in[0];
    const float* wq = (const float*)d_in[1];
    const float* wk = (const float*)d_in[2];
    const float* wv = (const float*)d_in[3];
    const float* wo = (const float*)d_in[4];
    const int*  pos = (const int*)d_in[5];

    float* ws   = (float*)d_ws;
    float* Qraw = ws;                        // 4096x1024 f32 (16 MB)
    float* Kraw = ws + 4194304;              // 4096x512  f32 ( 8 MB)
    float* Vraw = ws + 6291456;              // 4096x512  f32 ( 8 MB)
    unsigned short* KH = (unsigned short*)(ws + 8388608);  // 2M bf16 (4 MB)
    unsigned short* KL = KH + 2097152;                     // 4 MB
    unsigned short* VT = KL + 2097152;                     // 4 MB
    float* AO   = ws + 4194304;              // overlays Kraw+Vraw (16 MB) — safe: consumed by prep_k/prep_v
    float* out  = (float*)d_out;

    dim3 blk(256);
    gemm_tile<<<dim3(64, 8), blk, 0, stream>>>(hs, wq, Qraw, 1024, 1024);
    gemm_tile<<<dim3(64, 4), blk, 0, stream>>>(hs, wk, Kraw, 1024, 512);
    gemm_tile<<<dim3(64, 4), blk, 0, stream>>>(hs, wv, Vraw, 1024, 512);
    rope_q<<<dim3(8192), blk, 0, stream>>>(Qraw, pos);
    prep_k<<<dim3(8192), blk, 0, stream>>>(Kraw, KH, KL, pos);
    prep_v<<<dim3(512),  blk, 0, stream>>>(Vraw, VT);
    attn<<<dim3(4096), blk, 0, stream>>>(Qraw, KH, KL, VT, AO);
    gemm_tile<<<dim3(64, 8), blk, 0, stream>>>(AO, wo, out, 1024, 1024);
}

// Round 3
// 1308.228 us; speedup vs baseline: 1.4142x; 1.0146x over previous
//
#include <hip/hip_runtime.h>
#include <cstdint>
#include <cstddef>

typedef unsigned int u32;
typedef __attribute__((ext_vector_type(8))) short s8v;   // 8 bf16 (4 VGPRs)
typedef __attribute__((ext_vector_type(4))) float f4v;   // MFMA C/D

#define B_   2
#define L_   2048
#define D_   1024
#define NH_  16
#define KVH_ 8
#define DH_  64
#define TOPK_ 1024

#define MFMA16(a, b, c) __builtin_amdgcn_mfma_f32_16x16x32_bf16(a, b, c, 0, 0, 0)

// order-preserving float->uint key (descending float == descending uint)
__device__ __forceinline__ u32 fkey(float s) {
    u32 b = __float_as_uint(s);
    return b ^ ((u32)((int)b >> 31) | 0x80000000u);
}
// fp32 -> bf16 round-to-nearest-even, as raw ushort
__device__ __forceinline__ unsigned short bf16rne(float x) {
    u32 u = __float_as_uint(x);
    u32 r = (u + 0x7FFFu + ((u >> 16) & 1u)) >> 16;
    return (unsigned short)r;
}

// ---------------------------------------------------------------------------
// Generic tiled fp32 GEMM: C[M][N] = A[M][K] @ W[K][N]
// ---------------------------------------------------------------------------
__global__ __launch_bounds__(256) void gemm_tile(
    const float* __restrict__ A, const float* __restrict__ W,
    float* __restrict__ C, int K, int N) {
    __shared__ __align__(16) float As[16 * 64];
    __shared__ __align__(16) float Bs[16 * 128];
    int t  = threadIdx.x;
    int tx = t & 15, ty = t >> 4;
    int m0 = blockIdx.x * 64;
    int n0 = blockIdx.y * 128;

    float acc[4][8];
#pragma unroll
    for (int i = 0; i < 4; ++i)
#pragma unroll
        for (int j = 0; j < 8; ++j) acc[i][j] = 0.f;

    int aRow = t >> 2, aK4 = (t & 3) * 4;
    int bRow = t >> 4, bCol = (t & 15) * 8;

    for (int k0 = 0; k0 < K; k0 += 16) {
        float4 av = *(const float4*)(A + (size_t)(m0 + aRow) * K + k0 + aK4);
        As[(aK4 + 0) * 64 + aRow] = av.x;
        As[(aK4 + 1) * 64 + aRow] = av.y;
        As[(aK4 + 2) * 64 + aRow] = av.z;
        As[(aK4 + 3) * 64 + aRow] = av.w;
        float4 b0 = *(const float4*)(W + (size_t)(k0 + bRow) * N + n0 + bCol);
        float4 b1 = *(const float4*)(W + (size_t)(k0 + bRow) * N + n0 + bCol + 4);
        *(float4*)&Bs[bRow * 128 + bCol]     = b0;
        *(float4*)&Bs[bRow * 128 + bCol + 4] = b1;
        __syncthreads();
#pragma unroll
        for (int kk = 0; kk < 16; ++kk) {
            float4 af  = *(float4*)&As[kk * 64 + ty * 4];
            float4 bf0 = *(float4*)&Bs[kk * 128 + tx * 8];
            float4 bf1 = *(float4*)&Bs[kk * 128 + tx * 8 + 4];
            float a_[4] = {af.x, af.y, af.z, af.w};
            float b_[8] = {bf0.x, bf0.y, bf0.z, bf0.w, bf1.x, bf1.y, bf1.z, bf1.w};
#pragma unroll
            for (int i = 0; i < 4; ++i)
#pragma unroll
                for (int j = 0; j < 8; ++j)
                    acc[i][j] = fmaf(a_[i], b_[j], acc[i][j]);
        }
        __syncthreads();
    }
#pragma unroll
    for (int i = 0; i < 4; ++i) {
        float4 o0 = {acc[i][0], acc[i][1], acc[i][2], acc[i][3]};
        float4 o1 = {acc[i][4], acc[i][5], acc[i][6], acc[i][7]};
        size_t r = (size_t)(m0 + ty * 4 + i) * N + n0 + tx * 8;
        *(float4*)(C + r)     = o0;
        *(float4*)(C + r + 4) = o1;
    }
}

// ---------------------------------------------------------------------------
// RoPE on Q, in place. Layout [b][l][h][d].
// ---------------------------------------------------------------------------
__global__ __launch_bounds__(256) void rope_q(float* __restrict__ Q,
                                              const int* __restrict__ pos) {
    int tid = blockIdx.x * 256 + threadIdx.x;
    int dl = tid & 31;
    int h  = (tid >> 5) & 15;
    int l  = (tid >> 9) & 2047;
    int b  = tid >> 20;
    size_t base = ((size_t)(b * L_ + l) * NH_ + h) * DH_;
    float x1 = Q[base + dl];
    float x2 = Q[base + dl + 32];
    float p = (float)pos[b * L_ + l];
    float invf = (float)pow(10000.0, -(double)dl / 32.0);
    float a = p * invf;
    float s, c;
    sincosf(a, &s, &c);
    Q[base + dl]      = x1 * c - x2 * s;
    Q[base + dl + 32] = x2 * c + x1 * s;
}

// ---------------------------------------------------------------------------
// RoPE on K + hi/lo bf16 split, layout [b][kvh][l][d]
// ---------------------------------------------------------------------------
__global__ __launch_bounds__(256) void prep_k(const float* __restrict__ Kraw,
                                              unsigned short* __restrict__ KHp,
                                              unsigned short* __restrict__ KLp,
                                              const int* __restrict__ pos) {
    int tid = blockIdx.x * 256 + threadIdx.x;
    int d   = tid & 63;
    int l   = (tid >> 6) & 2047;
    int kvh = (tid >> 17) & 7;
    int b   = tid >> 20;
    size_t src = ((size_t)(b * L_ + l) * KVH_ + kvh) * DH_;
    float x  = Kraw[src + d];
    int dp   = (d < 32) ? d + 32 : d - 32;
    float xp = Kraw[src + dp];
    float p = (float)pos[b * L_ + l];
    int i = d & 31;
    float invf = (float)pow(10000.0, -(double)i / 32.0);
    float a = p * invf;
    float s, c;
    sincosf(a, &s, &c);
    float out = (d < 32) ? (x * c - xp * s) : (x * c + xp * s);
    unsigned short hi = bf16rne(out);
    float hf = __uint_as_float((u32)hi << 16);
    unsigned short lo = bf16rne(out - hf);
    size_t dst = ((size_t)(b * KVH_ + kvh) * L_ + l) * DH_ + d;
    KHp[dst] = hi;
    KLp[dst] = lo;
}

// ---------------------------------------------------------------------------
// V transpose to bf16: Vraw[b][l][kvh][d] -> VT[b][kvh][d][l]
// ---------------------------------------------------------------------------
__global__ __launch_bounds__(256) void prep_v(const float* __restrict__ Vraw,
                                              unsigned short* __restrict__ VTp) {
    __shared__ float tile[64 * 65];
    int bid = blockIdx.x;
    int lb  = bid & 31;
    int kvh = (bid >> 5) & 7;
    int b   = bid >> 8;
    int l0  = lb * 64;
    int t   = threadIdx.x;
#pragma unroll
    for (int i = 0; i < 16; ++i) {
        int idx = t + i * 256;
        int ll = idx >> 6, d = idx & 63;
        tile[ll * 65 + d] = Vraw[((size_t)(b * L_ + l0 + ll) * KVH_ + kvh) * DH_ + d];
    }
    __syncthreads();
#pragma unroll
    for (int i = 0; i < 16; ++i) {
        int idx = t + i * 256;
        int d = idx >> 6, ll = idx & 63;
        VTp[((size_t)(b * KVH_ + kvh) * DH_ + d) * L_ + l0 + ll] = bf16rne(tile[ll * 65 + d]);
    }
}

// ---------------------------------------------------------------------------
// Fused sparse attention, 16 q-rows per block, 512 threads (8 waves).
// Wave w owns j in [256w, 256w+256): 16 MFMA C-tiles -> S[16] (64 VGPR).
// grid = B*NH*(L/16) = 4096.
// Score layout (MFMA C): S[tj][r] = score(q = quad*4+r, j = 256w + 16tj + col)
// ---------------------------------------------------------------------------
__global__ __launch_bounds__(512, 4) void attn(
    const float* __restrict__ QR,
    const unsigned short* __restrict__ KH,
    const unsigned short* __restrict__ KL,
    const unsigned short* __restrict__ VT,
    float* __restrict__ AO) {

    __shared__ __align__(16) union {
        struct { float qtile[16 * 68]; u32 eqbuf[2048]; } p0;   // phase0 + tie ranking
        u32 hist[16 * 256];                                     // radix (16 KB)
        unsigned short pbuf[8][16 * 136];                       // per-wave P chunks (34 KB)
    } sm;
    __shared__ float outred[16 * 64];                           // fp32 atomic PV reduction
    __shared__ u32 sPref[16], sK[16], sNgt[16], sEqTot[16];
    __shared__ float wredM[16][8], wredZ[16][8], sInvZ[16];
    __shared__ u32 sCM, sRM, eqCnt;

    const int t = threadIdx.x;
    const int lane = t & 63, w = t >> 6;            // w in [0,8)
    const int quad = lane >> 4, col = lane & 15;
    const int bid = blockIdx.x;
    const int l0 = (bid & 127) * 16;
    const int h  = (bid >> 7) & 15;
    const int b  = bid >> 11;
    const int kvh = h >> 1;

    // ---- load Q tile (roped, fp32) into LDS; zero outred
    if (t < 256) {
        int q = t >> 4, d4 = (t & 15) * 4;
        *(float4*)&sm.p0.qtile[q * 68 + d4] =
            *(const float4*)(QR + ((size_t)((b * L_ + l0 + q) * NH_ + h)) * DH_ + d4);
    }
    if (t < 16) { sPref[t] = 0u; sNgt[t] = 0u; sK[t] = TOPK_; sEqTot[t] = 0u; }
    outred[t] = 0.f; outred[t + 512] = 0.f;
    __syncthreads();

    // ---- build A-frags (hi/lo): A[m=col][k = ks*32 + quad*8 + i]
    union FR { s8v v; unsigned short u[8]; };
    FR ah[2], al[2];
#pragma unroll
    for (int ks = 0; ks < 2; ++ks)
#pragma unroll
        for (int i = 0; i < 8; ++i) {
            float x = sm.p0.qtile[col * 68 + ks * 32 + quad * 8 + i];
            unsigned short hi = bf16rne(x);
            float hf = __uint_as_float((u32)hi << 16);
            ah[ks].u[i] = hi;
            al[ks].u[i] = bf16rne(x - hf);
        }
    __syncthreads();

    // ---- QK^T via MFMA, 4-term hi/lo (fp32-class accuracy for exact top-k)
    const size_t slabK = (size_t)(b * KVH_ + kvh) * L_ * DH_;
    const unsigned short* khp = KH + slabK;
    const unsigned short* klp = KL + slabK;
    f4v S[16];
#pragma unroll
    for (int tj = 0; tj < 16; ++tj) {
        int j0 = w * 256 + tj * 16;
        const unsigned short* kh8 = khp + (size_t)(j0 + col) * 64 + quad * 8;
        const unsigned short* kl8 = klp + (size_t)(j0 + col) * 64 + quad * 8;
        s8v bh0 = *(const s8v*)(kh8);
        s8v bh1 = *(const s8v*)(kh8 + 32);
        s8v bl0 = *(const s8v*)(kl8);
        s8v bl1 = *(const s8v*)(kl8 + 32);
        f4v c = {0.f, 0.f, 0.f, 0.f};
        c = MFMA16(ah[0].v, bh0, c);
        c = MFMA16(al[0].v, bh0, c);
        c = MFMA16(ah[1].v, bh1, c);
        c = MFMA16(al[1].v, bh1, c);
        c = MFMA16(ah[0].v, bl0, c);
        c = MFMA16(al[0].v, bl0, c);
        c = MFMA16(ah[1].v, bl1, c);
        c = MFMA16(al[1].v, bl1, c);
        S[tj] = c * 0.125f;   // DH^-0.5
    }

    // ---- exact top-1024 per row: 4-pass 8-bit radix select on fkey
    for (int pass = 0; pass < 4; ++pass) {
        int shift = 24 - 8 * pass;
#pragma unroll
        for (int i = 0; i < 8; ++i) sm.hist[t * 8 + i] = 0u;
        __syncthreads();
        u32 pm  = pass ? (0xFFFFFFFFu << (shift + 8)) : 0u;
        u32 pf0 = sPref[quad * 4 + 0], pf1 = sPref[quad * 4 + 1];
        u32 pf2 = sPref[quad * 4 + 2], pf3 = sPref[quad * 4 + 3];
#pragma unroll
        for (int tj = 0; tj < 16; ++tj) {
            u32 u;
            u = fkey(S[tj][0]); if ((u & pm) == pf0) atomicAdd(&sm.hist[(quad * 4 + 0) * 256 + ((u >> shift) & 255)], 1u);
            u = fkey(S[tj][1]); if ((u & pm) == pf1) atomicAdd(&sm.hist[(quad * 4 + 1) * 256 + ((u >> shift) & 255)], 1u);
            u = fkey(S[tj][2]); if ((u & pm) == pf2) atomicAdd(&sm.hist[(quad * 4 + 2) * 256 + ((u >> shift) & 255)], 1u);
            u = fkey(S[tj][3]); if ((u & pm) == pf3) atomicAdd(&sm.hist[(quad * 4 + 3) * 256 + ((u >> shift) & 255)], 1u);
        }
        __syncthreads();
        // wave w resolves rows 2w, 2w+1
#pragma unroll
        for (int rr = 0; rr < 2; ++rr) {
            int q = w * 2 + rr;
            u32* hq = &sm.hist[q * 256];
            u32 h0 = hq[4 * lane], h1 = hq[4 * lane + 1];
            u32 h2 = hq[4 * lane + 2], h3 = hq[4 * lane + 3];
            u32 s4 = h0 + h1 + h2 + h3;
            u32 v = s4;
            for (int off = 1; off < 64; off <<= 1) {
                u32 tmp = __shfl_down(v, off);
                if (lane + off < 64) v += tmp;
            }
            u32 g = v - s4;
            u32 kq = sK[q];
            u32 hb_[4] = {h0, h1, h2, h3};
#pragma unroll
            for (int bb = 3; bb >= 0; --bb) {
                u32 hb = hb_[bb];
                if (hb && g < kq && kq <= g + hb) {
                    sPref[q] |= ((u32)(4 * lane + bb)) << shift;
                    sK[q]   = kq - g;
                    sNgt[q] += g;
                }
                g += hb;
            }
        }
        __syncthreads();
    }

    // ---- selection masks (bit tj per reg r), exact tie handling
    u32 uth0 = sPref[quad * 4 + 0], uth1 = sPref[quad * 4 + 1];
    u32 uth2 = sPref[quad * 4 + 2], uth3 = sPref[quad * 4 + 3];
    u32 selb[4] = {0u, 0u, 0u, 0u};
    {
        u32 e0 = 0, e1 = 0, e2 = 0, e3 = 0;
#pragma unroll
        for (int tj = 0; tj < 16; ++tj) {
            u32 u;
            u = fkey(S[tj][0]); if (u > uth0) selb[0] |= 1u << tj; else if (u == uth0) e0++;
            u = fkey(S[tj][1]); if (u > uth1) selb[1] |= 1u << tj; else if (u == uth1) e1++;
            u = fkey(S[tj][2]); if (u > uth2) selb[2] |= 1u << tj; else if (u == uth2) e2++;
            u = fkey(S[tj][3]); if (u > uth3) selb[3] |= 1u << tj; else if (u == uth3) e3++;
        }
        if (e0) atomicAdd(&sEqTot[quad * 4 + 0], e0);
        if (e1) atomicAdd(&sEqTot[quad * 4 + 1], e1);
        if (e2) atomicAdd(&sEqTot[quad * 4 + 2], e2);
        if (e3) atomicAdd(&sEqTot[quad * 4 + 3], e3);
    }
    __syncthreads();
    if (t == 0) {
        u32 cm = 0, rm = 0;
        for (int q = 0; q < 16; ++q) {
            u32 quo = (u32)TOPK_ - sNgt[q];
            if (sEqTot[q] == quo) cm |= 1u << q; else rm |= 1u << q;
        }
        sCM = cm; sRM = rm;
    }
    __syncthreads();
    {
        u32 cm = sCM;
        bool c0 = (cm >> (quad * 4 + 0)) & 1u, c1 = (cm >> (quad * 4 + 1)) & 1u;
        bool c2 = (cm >> (quad * 4 + 2)) & 1u, c3 = (cm >> (quad * 4 + 3)) & 1u;
#pragma unroll
        for (int tj = 0; tj < 16; ++tj) {
            if (c0 && fkey(S[tj][0]) == uth0) selb[0] |= 1u << tj;
            if (c1 && fkey(S[tj][1]) == uth1) selb[1] |= 1u << tj;
            if (c2 && fkey(S[tj][2]) == uth2) selb[2] |= 1u << tj;
            if (c3 && fkey(S[tj][3]) == uth3) selb[3] |= 1u << tj;
        }
    }
    {   // rare rows: rank ties by lowest index
        u32 rm = sRM;
        for (int q = 0; q < 16; ++q) {
            if (!((rm >> q) & 1u)) continue;
            if (t == 0) eqCnt = 0u;
            __syncthreads();
            u32 uq = sPref[q];
            int qq = q >> 2, qr = q & 3;
            if (quad == qq) {
#pragma unroll
                for (int r = 0; r < 4; ++r) if (r == qr) {
#pragma unroll
                    for (int tj = 0; tj < 16; ++tj)
                        if (fkey(S[tj][r]) == uq) {
                            u32 idx = atomicAdd(&eqCnt, 1u);
                            if (idx < 2048u) sm.p0.eqbuf[idx] = (u32)(w * 256 + tj * 16 + col);
                        }
                }
            }
            __syncthreads();
            u32 m = eqCnt; if (m > 2048u) m = 2048u;
            u32 quo = (u32)TOPK_ - sNgt[q];
            if (quad == qq) {
#pragma unroll
                for (int r = 0; r < 4; ++r) if (r == qr) {
#pragma unroll
                    for (int tj = 0; tj < 16; ++tj)
                        if (fkey(S[tj][r]) == uq) {
                            u32 j = (u32)(w * 256 + tj * 16 + col);
                            u32 rk = 0;
                            for (u32 i = 0; i < m; ++i)
                                if (sm.p0.eqbuf[i] < j) rk++;
                            if (rk < quo) selb[r] |= 1u << tj;
                        }
                }
            }
            __syncthreads();
        }
    }

    // ---- softmax (row max over all scores; top element always selected)
    float m0 = -3.4e38f, m1 = -3.4e38f, m2 = -3.4e38f, m3 = -3.4e38f;
#pragma unroll
    for (int tj = 0; tj < 16; ++tj) {
        m0 = fmaxf(m0, S[tj][0]); m1 = fmaxf(m1, S[tj][1]);
        m2 = fmaxf(m2, S[tj][2]); m3 = fmaxf(m3, S[tj][3]);
    }
    for (int off = 1; off < 16; off <<= 1) {
        m0 = fmaxf(m0, __shfl_xor(m0, off)); m1 = fmaxf(m1, __shfl_xor(m1, off));
        m2 = fmaxf(m2, __shfl_xor(m2, off)); m3 = fmaxf(m3, __shfl_xor(m3, off));
    }
    if (col == 0) {
        wredM[quad * 4 + 0][w] = m0; wredM[quad * 4 + 1][w] = m1;
        wredM[quad * 4 + 2][w] = m2; wredM[quad * 4 + 3][w] = m3;
    }
    __syncthreads();
    {
        float a0 = wredM[quad * 4 + 0][0], a1 = wredM[quad * 4 + 1][0];
        float a2 = wredM[quad * 4 + 2][0], a3 = wredM[quad * 4 + 3][0];
#pragma unroll
        for (int ww = 1; ww < 8; ++ww) {
            a0 = fmaxf(a0, wredM[quad * 4 + 0][ww]); a1 = fmaxf(a1, wredM[quad * 4 + 1][ww]);
            a2 = fmaxf(a2, wredM[quad * 4 + 2][ww]); a3 = fmaxf(a3, wredM[quad * 4 + 3][ww]);
        }
        m0 = a0; m1 = a1; m2 = a2; m3 = a3;
    }
    float z0 = 0.f, z1 = 0.f, z2 = 0.f, z3 = 0.f;
#pragma unroll
    for (int tj = 0; tj < 16; ++tj) {
        float e;
        e = ((selb[0] >> tj) & 1u) ? __expf(S[tj][0] - m0) : 0.f; S[tj][0] = e; z0 += e;
        e = ((selb[1] >> tj) & 1u) ? __expf(S[tj][1] - m1) : 0.f; S[tj][1] = e; z1 += e;
        e = ((selb[2] >> tj) & 1u) ? __expf(S[tj][2] - m2) : 0.f; S[tj][2] = e; z2 += e;
        e = ((selb[3] >> tj) & 1u) ? __expf(S[tj][3] - m3) : 0.f; S[tj][3] = e; z3 += e;
    }
    for (int off = 1; off < 16; off <<= 1) {
        z0 += __shfl_xor(z0, off); z1 += __shfl_xor(z1, off);
        z2 += __shfl_xor(z2, off); z3 += __shfl_xor(z3, off);
    }
    if (col == 0) {
        wredZ[quad * 4 + 0][w] = z0; wredZ[quad * 4 + 1][w] = z1;
        wredZ[quad * 4 + 2][w] = z2; wredZ[quad * 4 + 3][w] = z3;
    }
    __syncthreads();
    if (w == 0 && col == 0) {
#pragma unroll
        for (int r = 0; r < 4; ++r) {
            int q = quad * 4 + r;
            float Z = 0.f;
#pragma unroll
            for (int ww = 0; ww < 8; ++ww) Z += wredZ[q][ww];
            sInvZ[q] = 1.f / Z;
        }
    }

    // ---- PV via MFMA; wave w covers its own 256-col j-range in 2 chunks of 128.
    const unsigned short* vt = VT + (size_t)(b * KVH_ + kvh) * DH_ * L_;
    f4v acc0 = {0.f, 0.f, 0.f, 0.f}, acc1 = acc0, acc2 = acc0, acc3 = acc0;
#pragma unroll
    for (int cc = 0; cc < 2; ++cc) {
        // write P chunk (C-layout -> row-major [q][jl]) — wave-private region
#pragma unroll
        for (int tjl = 0; tjl < 8; ++tjl) {
            int tj = cc * 8 + tjl;
            sm.pbuf[w][(quad * 4 + 0) * 136 + tjl * 16 + col] = bf16rne(S[tj][0]);
            sm.pbuf[w][(quad * 4 + 1) * 136 + tjl * 16 + col] = bf16rne(S[tj][1]);
            sm.pbuf[w][(quad * 4 + 2) * 136 + tjl * 16 + col] = bf16rne(S[tj][2]);
            sm.pbuf[w][(quad * 4 + 3) * 136 + tjl * 16 + col] = bf16rne(S[tj][3]);
        }
        // same-wave DS ordering guarantees write->read consistency
#pragma unroll
        for (int ks = 0; ks < 4; ++ks) {
            s8v ap = *(const s8v*)&sm.pbuf[w][col * 136 + ks * 32 + quad * 8];
            int jb = w * 256 + cc * 128 + ks * 32 + quad * 8;
            s8v v0 = *(const s8v*)(vt + (size_t)( 0 + col) * L_ + jb);
            s8v v1 = *(const s8v*)(vt + (size_t)(16 + col) * L_ + jb);
            s8v v2 = *(const s8v*)(vt + (size_t)(32 + col) * L_ + jb);
            s8v v3 = *(const s8v*)(vt + (size_t)(48 + col) * L_ + jb);
            acc0 = MFMA16(ap, v0, acc0);
            acc1 = MFMA16(ap, v1, acc1);
            acc2 = MFMA16(ap, v2, acc2);
            acc3 = MFMA16(ap, v3, acc3);
        }
    }

    // ---- cross-wave PV reduction via LDS fp32 atomics, then scale + store
#pragma unroll
    for (int r = 0; r < 4; ++r) {
        atomicAdd(&outred[(quad * 4 + r) * 64 +  0 + col], acc0[r]);
        atomicAdd(&outred[(quad * 4 + r) * 64 + 16 + col], acc1[r]);
        atomicAdd(&outred[(quad * 4 + r) * 64 + 32 + col], acc2[r]);
        atomicAdd(&outred[(quad * 4 + r) * 64 + 48 + col], acc3[r]);
    }
    __syncthreads();
    if (t < 256) {
        int q = t >> 4, d4 = (t & 15) * 4;
        float4 o = *(float4*)&outred[q * 64 + d4];
        float iz = sInvZ[q];
        o.x *= iz; o.y *= iz; o.z *= iz; o.w *= iz;
        *(float4*)(AO + ((size_t)((b * L_ + l0 + q) * NH_ + h)) * DH_ + d4) = o;
    }
}

// ---------------------------------------------------------------------------
extern "C" void kernel_launch(void* const* d_in, const int* in_sizes, int n_in,
                              void* d_out, int out_size, void* d_ws, size_t ws_size,
                              hipStream_t stream) {
    const float* hs = (const float*)d_in[0];
    const float* wq = (const float*)d_in[1];
    const float* wk = (const float*)d_in[2];
    const float* wv = (const float*)d_in[3];
    const float* wo = (const float*)d_in[4];
    const int*  pos = (const int*)d_in[5];

    float* ws   = (float*)d_ws;
    float* Qraw = ws;                        // 4096x1024 f32 (16 MB)
    float* Kraw = ws + 4194304;              // 4096x512  f32 ( 8 MB)
    float* Vraw = ws + 6291456;              // 4096x512  f32 ( 8 MB)
    unsigned short* KH = (unsigned short*)(ws + 8388608);  // 4 MB
    unsigned short* KL = KH + 2097152;                     // 4 MB
    unsigned short* VT = KL + 2097152;                     // 4 MB
    float* AO   = ws + 4194304;              // overlays Kraw+Vraw — consumed by prep_k/prep_v first
    float* out  = (float*)d_out;

    dim3 blk(256);
    gemm_tile<<<dim3(64, 8), blk, 0, stream>>>(hs, wq, Qraw, 1024, 1024);
    gemm_tile<<<dim3(64, 4), blk, 0, stream>>>(hs, wk, Kraw, 1024, 512);
    gemm_tile<<<dim3(64, 4), blk, 0, stream>>>(hs, wv, Vraw, 1024, 512);
    rope_q<<<dim3(8192), blk, 0, stream>>>(Qraw, pos);
    prep_k<<<dim3(8192), blk, 0, stream>>>(Kraw, KH, KL, pos);
    prep_v<<<dim3(512),  blk, 0, stream>>>(Vraw, VT);
    attn<<<dim3(4096), dim3(512), 0, stream>>>(Qraw, KH, KL, VT, AO);
    gemm_tile<<<dim3(64, 8), blk, 0, stream>>>(AO, wo, out, 1024, 1024);
}